// Round 2
// baseline (1920.493 us; speedup 1.0000x reference)
//
#include <hip/hip_runtime.h>

// VectorQuantizer forward: out = codebook[argmin_k ||x - e_k||^2]
// inputs:  d_in[0] = inputs  [32,64,64,64] fp32  (N=131072 rows, D=64)
//          d_in[1] = embeddings [64,512] fp32    (D=64, K=512)
// out:     [32,64,64,64] fp32
//
// R2: 4-way k-split per row (4 lanes/row in-wave) -> 4x waves (latency hiding)
//     + e-loads become vector loads (deep vmcnt pipelining) instead of s_load.

#define KC 512
#define DD 64
#define SPLIT 4
#define KPT (KC / SPLIT)   // 128 codes per thread

// Precompute E^T (K x D, row-contiguous) and bias_k = ||e_k||^2 into workspace.
__global__ void vq_prep(const float* __restrict__ emb,
                        float* __restrict__ et, float* __restrict__ bias) {
    int k = blockIdx.x * blockDim.x + threadIdx.x;
    if (k >= KC) return;
    float s = 0.f;
    #pragma unroll
    for (int d = 0; d < DD; ++d) {
        float v = emb[d * KC + k];
        et[k * DD + d] = v;
        s += v * v;
    }
    bias[k] = s;
}

__global__ __launch_bounds__(256) void vq_main(const float* __restrict__ x_in,
                                               const float* __restrict__ et,
                                               const float* __restrict__ bias,
                                               float* __restrict__ out) {
    const int tid    = threadIdx.x;
    const int t      = tid & (SPLIT - 1);     // k-split id, 0..3
    const int rlocal = tid >> 2;              // 0..63
    const int row    = blockIdx.x * 64 + rlocal;

    // Load the full x row (4 lanes per row load the same data; same cache
    // lines within the wave, so no extra HBM traffic).
    float x[DD];
    {
        const float4* xin4 = (const float4*)(x_in + (size_t)row * DD);
        #pragma unroll
        for (int i = 0; i < DD / 4; ++i) {
            float4 v = xin4[i];
            x[4 * i + 0] = v.x;
            x[4 * i + 1] = v.y;
            x[4 * i + 2] = v.z;
            x[4 * i + 3] = v.w;
        }
    }

    const float* ebase = et + (size_t)t * KPT * DD;   // per-lane-group base
    const float* bbase = bias + t * KPT;

    float minv = 3.4e38f;
    int   mink = 0;

    #pragma unroll 2
    for (int j = 0; j < KPT; ++j) {
        const float4* e4 = (const float4*)(ebase + (size_t)j * DD);
        float a0 = 0.f, a1 = 0.f, a2 = 0.f, a3 = 0.f;
        #pragma unroll
        for (int i = 0; i < DD / 4; ++i) {
            float4 e = e4[i];
            a0 += x[4 * i + 0] * e.x;
            a1 += x[4 * i + 1] * e.y;
            a2 += x[4 * i + 2] * e.z;
            a3 += x[4 * i + 3] * e.w;
        }
        float dot = (a0 + a1) + (a2 + a3);
        float s = bbase[j] - 2.f * dot;       // ||x||^2 term argmin-invariant
        if (s < minv) { minv = s; mink = j; } // strict <: first index wins ties
    }
    mink += t * KPT;

    // Reduce (min, argmin) across the 4 lanes of this row group.
    // Tie-break: smaller k wins (numpy argmin first-min semantics).
    #pragma unroll
    for (int m = 1; m <= 2; m <<= 1) {
        float ov = __shfl_xor(minv, m, 64);
        int   ok = __shfl_xor(mink, m, 64);
        if (ov < minv || (ov == minv && ok < mink)) { minv = ov; mink = ok; }
    }

    // All 4 lanes of the group agree on mink. Cooperative output write:
    // lane t writes floats [t*16, t*16+16). out == e[mink] (x + (q-x) == q
    // to ~3e-7, far below the 4.3e-3 threshold).
    const float4* eq = (const float4*)(et + (size_t)mink * DD + t * 16);
    float4*       op = (float4*)(out + (size_t)row * DD + t * 16);
    #pragma unroll
    for (int i = 0; i < 4; ++i) op[i] = eq[i];
}

extern "C" void kernel_launch(void* const* d_in, const int* in_sizes, int n_in,
                              void* d_out, int out_size, void* d_ws, size_t ws_size,
                              hipStream_t stream) {
    const float* x_in = (const float*)d_in[0];   // [131072, 64]
    const float* emb  = (const float*)d_in[1];   // [64, 512]
    float* out = (float*)d_out;

    float* et   = (float*)d_ws;                  // [512, 64]
    float* bias = et + KC * DD;                  // [512]

    const int N = out_size / DD;                 // 131072 rows

    vq_prep<<<(KC + 255) / 256, 256, 0, stream>>>(emb, et, bias);
    vq_main<<<N / 64, 256, 0, stream>>>(x_in, et, bias, out);
}

// Round 3
// 256.044 us; speedup vs baseline: 7.5006x; 7.5006x over previous
//
#include <hip/hip_runtime.h>

// VectorQuantizer forward: out = codebook[argmin_k ||x - e_k||^2]
// inputs:  d_in[0] = inputs  [32,64,64,64] fp32  (N=131072 rows, D=64)
//          d_in[1] = embeddings [64,512] fp32    (D=64, K=512)
// out:     [32,64,64,64] fp32
//
// R3: wave-level k-split. Block = 4 waves x same 64 rows; wave w scans codes
//     [w*128,(w+1)*128) with WAVE-UNIFORM e-addresses (forced scalar path via
//     readfirstlane) -> s_load streaming like R1, but 4x the waves for latency
//     hiding. Block-level (min,argmin) merge through LDS.

#define KC 512
#define DD 64
#define NWAVE 4
#define KPT (KC / NWAVE)   // 128 codes per wave

// Precompute E^T (K x D, row-contiguous) and bias_k = ||e_k||^2 into workspace.
__global__ void vq_prep(const float* __restrict__ emb,
                        float* __restrict__ et, float* __restrict__ bias) {
    int k = blockIdx.x * blockDim.x + threadIdx.x;
    if (k >= KC) return;
    float s = 0.f;
    #pragma unroll
    for (int d = 0; d < DD; ++d) {
        float v = emb[d * KC + k];
        et[k * DD + d] = v;
        s += v * v;
    }
    bias[k] = s;
}

__global__ __launch_bounds__(256) void vq_main(const float* __restrict__ x_in,
                                               const float* __restrict__ et,
                                               const float* __restrict__ bias,
                                               float* __restrict__ out) {
    __shared__ float vbuf[NWAVE * 64];
    __shared__ int   kbuf[NWAVE * 64];

    const int tid  = threadIdx.x;
    const int lane = tid & 63;
    // Force wave-uniformity into an SGPR so the e-stream stays on s_load.
    const int wid  = __builtin_amdgcn_readfirstlane(tid >> 6);
    const int row  = blockIdx.x * 64 + lane;

    // Row lives in VGPRs (compile-time-constant indexing only!).
    float x[DD];
    {
        const float4* xin4 = (const float4*)(x_in + (size_t)row * DD);
        #pragma unroll
        for (int i = 0; i < DD / 4; ++i) {
            float4 v = xin4[i];
            x[4 * i + 0] = v.x;
            x[4 * i + 1] = v.y;
            x[4 * i + 2] = v.z;
            x[4 * i + 3] = v.w;
        }
    }

    const float* ebase = et + (size_t)wid * KPT * DD;  // wave-uniform
    const float* bbase = bias + wid * KPT;

    float minv = 3.4e38f;
    int   mink = 0;

    #pragma unroll 2
    for (int j = 0; j < KPT; ++j) {
        const float* ek = ebase + (size_t)j * DD;      // uniform -> s_load
        float a0 = 0.f, a1 = 0.f, a2 = 0.f, a3 = 0.f;
        #pragma unroll
        for (int d = 0; d < DD; d += 4) {
            a0 += x[d + 0] * ek[d + 0];
            a1 += x[d + 1] * ek[d + 1];
            a2 += x[d + 2] * ek[d + 2];
            a3 += x[d + 3] * ek[d + 3];
        }
        float dot = (a0 + a1) + (a2 + a3);
        float s = bbase[j] - 2.f * dot;       // identical arithmetic to R1
        if (s < minv) { minv = s; mink = j; } // strict <: first index wins
    }

    vbuf[wid * 64 + lane] = minv;
    kbuf[wid * 64 + lane] = wid * KPT + mink;
    __syncthreads();

    // Merge the 4 wave-candidates for this lane's row. Ascending w = ascending
    // k-ranges, so strict < reproduces numpy's global first-min tie-breaking.
    float best = vbuf[lane];
    int   bk   = kbuf[lane];
    #pragma unroll
    for (int w = 1; w < NWAVE; ++w) {
        float v = vbuf[w * 64 + lane];
        int   k = kbuf[w * 64 + lane];
        if (v < best) { best = v; bk = k; }
    }

    // Cooperative output: thread (wid,lane) writes floats [wid*16, wid*16+16)
    // of its row as x + (q - x) (R1's exact output arithmetic, absmax 0).
    // Re-read the x slice from global (L1-hot) — indexing x[] by runtime wid
    // would force the register array to scratch.
    const float4* eq = (const float4*)(et  + (size_t)bk  * DD + wid * 16);
    const float4* xs = (const float4*)(x_in + (size_t)row * DD + wid * 16);
    float4*       op = (float4*)(out + (size_t)row * DD + wid * 16);
    #pragma unroll
    for (int i = 0; i < 4; ++i) {
        float4 q = eq[i], xv = xs[i], o;
        o.x = xv.x + (q.x - xv.x);
        o.y = xv.y + (q.y - xv.y);
        o.z = xv.z + (q.z - xv.z);
        o.w = xv.w + (q.w - xv.w);
        op[i] = o;
    }
}

extern "C" void kernel_launch(void* const* d_in, const int* in_sizes, int n_in,
                              void* d_out, int out_size, void* d_ws, size_t ws_size,
                              hipStream_t stream) {
    const float* x_in = (const float*)d_in[0];   // [131072, 64]
    const float* emb  = (const float*)d_in[1];   // [64, 512]
    float* out = (float*)d_out;

    float* et   = (float*)d_ws;                  // [512, 64]
    float* bias = et + KC * DD;                  // [512]

    const int N = out_size / DD;                 // 131072 rows

    vq_prep<<<(KC + 255) / 256, 256, 0, stream>>>(emb, et, bias);
    vq_main<<<N / 64, 256, 0, stream>>>(x_in, et, bias, out);
}

// Round 4
// 255.424 us; speedup vs baseline: 7.5188x; 1.0024x over previous
//
#include <hip/hip_runtime.h>

// VectorQuantizer forward: out = codebook[argmin_k ||x - e_k||^2]
// inputs:  d_in[0] = inputs  [32,64,64,64] fp32  (N=131072 rows, D=64)
//          d_in[1] = embeddings [64,512] fp32    (D=64, K=512)
// out:     [32,64,64,64] fp32
//
// R4: R3 structure (wave-level k-split, scalar e-stream) + register fix:
//     __launch_bounds__(256,1) so x[64] stays in arch VGPRs (R3's VGPR=60
//     proved x was spilled to AGPRs -> v_accvgpr_read per FMA = 3x VALU
//     inflation). Outer unroll removed to cut live-range pressure.
//     vq_prep rewritten as coalesced LDS-tile transpose (was 48 us).

#define KC 512
#define DD 64
#define NWAVE 4
#define KPT (KC / NWAVE)   // 128 codes per wave

// Transpose emb [64,512] -> et [512,64] and bias_k = ||e_k||^2 (exact R1
// summation order: d = 0..63 sequential). 8 blocks x 256 threads.
__global__ __launch_bounds__(256) void vq_prep(const float* __restrict__ emb,
                                               float* __restrict__ et,
                                               float* __restrict__ bias) {
    __shared__ float tile[DD][DD + 1];
    const int b    = blockIdx.x;          // code group [b*64, b*64+64)
    const int lane = threadIdx.x & 63;
    const int q    = threadIdx.x >> 6;    // 0..3

    // Coalesced load: row d, 64 consecutive codes.
    #pragma unroll
    for (int i = 0; i < 16; ++i) {
        int d = q + 4 * i;
        tile[d][lane] = emb[d * KC + b * 64 + lane];
    }
    __syncthreads();

    // Coalesced store: thread (kl,seg) writes floats [seg*16, seg*16+16) of
    // code row kl.
    const int kl  = threadIdx.x >> 2;     // 0..63
    const int seg = threadIdx.x & 3;      // 0..3
    float4* op = (float4*)(et + ((size_t)(b * 64 + kl)) * DD + seg * 16);
    #pragma unroll
    for (int i = 0; i < 4; ++i) {
        float4 v;
        v.x = tile[seg * 16 + 4 * i + 0][kl];
        v.y = tile[seg * 16 + 4 * i + 1][kl];
        v.z = tile[seg * 16 + 4 * i + 2][kl];
        v.w = tile[seg * 16 + 4 * i + 3][kl];
        op[i] = v;
    }

    // bias in exact sequential d-order (matches R1/R3 numerics bit-for-bit).
    if (threadIdx.x < 64) {
        float s = 0.f;
        #pragma unroll
        for (int d = 0; d < DD; ++d) {
            float v = tile[d][threadIdx.x];
            s += v * v;
        }
        bias[b * 64 + threadIdx.x] = s;
    }
}

__global__ __launch_bounds__(256, 1) void vq_main(const float* __restrict__ x_in,
                                                  const float* __restrict__ et,
                                                  const float* __restrict__ bias,
                                                  float* __restrict__ out) {
    __shared__ float vbuf[NWAVE * 64];
    __shared__ int   kbuf[NWAVE * 64];

    const int tid  = threadIdx.x;
    const int lane = tid & 63;
    // Force wave-uniformity into an SGPR so the e-stream stays on s_load.
    const int wid  = __builtin_amdgcn_readfirstlane(tid >> 6);
    const int row  = blockIdx.x * 64 + lane;

    // Row lives in VGPRs (compile-time-constant indexing only).
    float x[DD];
    {
        const float4* xin4 = (const float4*)(x_in + (size_t)row * DD);
        #pragma unroll
        for (int i = 0; i < DD / 4; ++i) {
            float4 v = xin4[i];
            x[4 * i + 0] = v.x;
            x[4 * i + 1] = v.y;
            x[4 * i + 2] = v.z;
            x[4 * i + 3] = v.w;
        }
    }

    const float* ebase = et + (size_t)wid * KPT * DD;  // wave-uniform
    const float* bbase = bias + wid * KPT;

    float minv = 3.4e38f;
    int   mink = 0;

    #pragma unroll 1
    for (int j = 0; j < KPT; ++j) {
        const float* ek = ebase + (size_t)j * DD;      // uniform -> s_load
        float a0 = 0.f, a1 = 0.f, a2 = 0.f, a3 = 0.f;
        #pragma unroll
        for (int d = 0; d < DD; d += 4) {
            a0 += x[d + 0] * ek[d + 0];
            a1 += x[d + 1] * ek[d + 1];
            a2 += x[d + 2] * ek[d + 2];
            a3 += x[d + 3] * ek[d + 3];
        }
        float dot = (a0 + a1) + (a2 + a3);
        float s = bbase[j] - 2.f * dot;       // identical arithmetic to R1/R3
        if (s < minv) { minv = s; mink = j; } // strict <: first index wins
    }

    vbuf[wid * 64 + lane] = minv;
    kbuf[wid * 64 + lane] = wid * KPT + mink;
    __syncthreads();

    // Merge the 4 wave-candidates for this row. Ascending w = ascending
    // k-ranges, so strict < reproduces numpy's first-min tie-breaking.
    float best = vbuf[lane];
    int   bk   = kbuf[lane];
    #pragma unroll
    for (int w = 1; w < NWAVE; ++w) {
        float v = vbuf[w * 64 + lane];
        int   k = kbuf[w * 64 + lane];
        if (v < best) { best = v; bk = k; }
    }

    // Cooperative output: thread (wid,lane) writes floats [wid*16,wid*16+16)
    // of its row as x + (q - x) (exact R1 output arithmetic).
    const float4* eq = (const float4*)(et   + (size_t)bk  * DD + wid * 16);
    const float4* xs = (const float4*)(x_in + (size_t)row * DD + wid * 16);
    float4*       op = (float4*)(out + (size_t)row * DD + wid * 16);
    #pragma unroll
    for (int i = 0; i < 4; ++i) {
        float4 qv = eq[i], xv = xs[i], o;
        o.x = xv.x + (qv.x - xv.x);
        o.y = xv.y + (qv.y - xv.y);
        o.z = xv.z + (qv.z - xv.z);
        o.w = xv.w + (qv.w - xv.w);
        op[i] = o;
    }
}

extern "C" void kernel_launch(void* const* d_in, const int* in_sizes, int n_in,
                              void* d_out, int out_size, void* d_ws, size_t ws_size,
                              hipStream_t stream) {
    const float* x_in = (const float*)d_in[0];   // [131072, 64]
    const float* emb  = (const float*)d_in[1];   // [64, 512]
    float* out = (float*)d_out;

    float* et   = (float*)d_ws;                  // [512, 64]
    float* bias = et + KC * DD;                  // [512]

    const int N = out_size / DD;                 // 131072 rows

    vq_prep<<<KC / 64, 256, 0, stream>>>(emb, et, bias);
    vq_main<<<N / 64, 256, 0, stream>>>(x_in, et, bias, out);
}

// Round 5
// 190.298 us; speedup vs baseline: 10.0920x; 1.3422x over previous
//
#include <hip/hip_runtime.h>

// VectorQuantizer forward: out = codebook[argmin_k ||x - e_k||^2]
// inputs:  d_in[0] = inputs  [32,64,64,64] fp32  (N=131072 rows, D=64)
//          d_in[1] = embeddings [64,512] fp32    (D=64, K=512)
// out:     [32,64,64,64] fp32
//
// R5: register-blocked LDS GEMM. R3/R4 proved the compiler won't keep x[64]
//     in arch VGPRs (VGPR=60 both rounds -> ~3x VALU inflation via AGPR/L1
//     round-trips). New structure: x-tile (64 rows) transposed in LDS,
//     codebook streamed through LDS in 4x128-code chunks, each thread owns a
//     4-row x 8-code accumulator tile (32 independent fmac chains, ~93% of
//     VALU insts are fmac). Argmin merged via LDS with (v,k) tie-break.

#define KC 512
#define DD 64
#define RB 64          // rows per block
#define CH 128         // codes per LDS chunk
#define NCH (KC / CH)  // 4

// Transpose emb [64,512] -> et [512,64] and bias_k = ||e_k||^2 (sequential
// d-order). et is used only for the coalesced gather epilogue.
__global__ __launch_bounds__(256) void vq_prep(const float* __restrict__ emb,
                                               float* __restrict__ et,
                                               float* __restrict__ bias) {
    __shared__ float tile[DD][DD + 1];
    const int b    = blockIdx.x;          // code group [b*64, b*64+64)
    const int lane = threadIdx.x & 63;
    const int q    = threadIdx.x >> 6;    // 0..3

    #pragma unroll
    for (int i = 0; i < 16; ++i) {
        int d = q + 4 * i;
        tile[d][lane] = emb[d * KC + b * 64 + lane];
    }
    __syncthreads();

    const int kl  = threadIdx.x >> 2;     // 0..63
    const int seg = threadIdx.x & 3;      // 0..3
    float4* op = (float4*)(et + ((size_t)(b * 64 + kl)) * DD + seg * 16);
    #pragma unroll
    for (int i = 0; i < 4; ++i) {
        float4 v;
        v.x = tile[seg * 16 + 4 * i + 0][kl];
        v.y = tile[seg * 16 + 4 * i + 1][kl];
        v.z = tile[seg * 16 + 4 * i + 2][kl];
        v.w = tile[seg * 16 + 4 * i + 3][kl];
        op[i] = v;
    }

    if (threadIdx.x < 64) {
        float s = 0.f;
        #pragma unroll
        for (int d = 0; d < DD; ++d) {
            float v = tile[d][threadIdx.x];
            s += v * v;
        }
        bias[b * 64 + threadIdx.x] = s;
    }
}

__global__ __launch_bounds__(256, 2) void vq_main(const float* __restrict__ x_in,
                                                  const float* __restrict__ emb,
                                                  const float* __restrict__ et,
                                                  const float* __restrict__ bias,
                                                  float* __restrict__ out) {
    __shared__ float xs[DD][RB + 4];   // 64x68: rows 16B-aligned, 2-way banks (free)
    __shared__ float es[DD][CH];       // 64x128 = 32 KB
    float* vb = &es[0][0];             // overlay after last chunk: [16][64] best val
    int*   kb = (int*)&es[8][0];       // [16][64] best k
    int*   kf = (int*)&xs[0][0];       // [64] final code per row (overlay on xs)

    const int t  = threadIdx.x;
    const int w  = t >> 6;                 // wave 0..3
    const int l  = t & 63;
    const int rg = l & 15;                 // rows 4rg..4rg+3
    const int cg = (w << 2) | (l >> 4);    // codes 8cg..8cg+7 within chunk
    const int row0 = blockIdx.x * RB;

    // ---- stage x-tile transposed: xs[d][r] = x_in[row0+r][d]
    {
        const int r  = t >> 2;
        const int d0 = (t & 3) * 16;
        const float4* xp = (const float4*)(x_in + (size_t)(row0 + r) * DD + d0);
        float xv[16];
        *(float4*)&xv[0]  = xp[0];
        *(float4*)&xv[4]  = xp[1];
        *(float4*)&xv[8]  = xp[2];
        *(float4*)&xv[12] = xp[3];
        #pragma unroll
        for (int i = 0; i < 16; ++i) xs[d0 + i][r] = xv[i];
    }

    float bestv[4] = {3.4e38f, 3.4e38f, 3.4e38f, 3.4e38f};
    int   bestk[4] = {0, 0, 0, 0};

    #pragma unroll 1
    for (int ch = 0; ch < NCH; ++ch) {
        const int c0 = ch * CH;
        __syncthreads();  // prev chunk's es readers done (also orders xs stores once)

        // ---- stage es[d][j] = emb[d][c0+j]  (coalesced 512B per half-wave)
        {
            const int jj = (l & 31) * 4;
            const int dh = l >> 5;
            #pragma unroll
            for (int i = 0; i < 8; ++i) {
                const int d = 16 * w + 2 * i + dh;
                float4 v = *(const float4*)(emb + (size_t)d * KC + c0 + jj);
                *(float4*)&es[d][jj] = v;
            }
        }
        __syncthreads();

        float acc[4][8];
        #pragma unroll
        for (int r = 0; r < 4; ++r)
            #pragma unroll
            for (int c = 0; c < 8; ++c) acc[r][c] = 0.f;

        #pragma unroll 8
        for (int k = 0; k < DD; ++k) {
            float4 xv = *(const float4*)&xs[k][4 * rg];       // broadcast x4
            float4 e0 = *(const float4*)&es[k][8 * cg];       // e8
            float4 e1 = *(const float4*)&es[k][8 * cg + 4];
            float xr[4] = {xv.x, xv.y, xv.z, xv.w};
            float ec[8] = {e0.x, e0.y, e0.z, e0.w, e1.x, e1.y, e1.z, e1.w};
            #pragma unroll
            for (int r = 0; r < 4; ++r)
                #pragma unroll
                for (int c = 0; c < 8; ++c)
                    acc[r][c] += xr[r] * ec[c];               // 32 indep chains
        }

        // fold chunk scores into running (best, bestk); per-thread scan is
        // k-ascending so strict < = first-min.
        #pragma unroll
        for (int c = 0; c < 8; ++c) {
            const int kk = c0 + 8 * cg + c;
            const float b = bias[kk];
            #pragma unroll
            for (int r = 0; r < 4; ++r) {
                float s = b - 2.f * acc[r][c];
                if (s < bestv[r]) { bestv[r] = s; bestk[r] = kk; }
            }
        }
    }

    __syncthreads();  // all es/xs reads done; safe to overlay vb/kb/kf
    #pragma unroll
    for (int r = 0; r < 4; ++r) {
        vb[cg * 64 + 4 * rg + r] = bestv[r];
        kb[cg * 64 + 4 * rg + r] = bestk[r];
    }
    __syncthreads();

    // merge 16 candidates per row; explicit (v,k) tie-break = numpy first-min
    if (t < 64) {
        float bv = vb[t];
        int   bk = kb[t];
        #pragma unroll
        for (int g = 1; g < 16; ++g) {
            float v = vb[g * 64 + t];
            int   k = kb[g * 64 + t];
            if (v < bv || (v == bv && k < bk)) { bv = v; bk = k; }
        }
        kf[t] = bk;
    }
    __syncthreads();

    // gather epilogue: thread (r,seg) writes floats [seg*16, seg*16+16) of its
    // row as x + (q - x) (exact R1 output arithmetic), q from transposed et.
    {
        const int r = t >> 2, seg = t & 3;
        const int bk = kf[r];
        const float4* eq = (const float4*)(et   + (size_t)bk * DD + seg * 16);
        const float4* xp = (const float4*)(x_in + (size_t)(row0 + r) * DD + seg * 16);
        float4*       op = (float4*)(out + (size_t)(row0 + r) * DD + seg * 16);
        #pragma unroll
        for (int i = 0; i < 4; ++i) {
            float4 q = eq[i], xv = xp[i], o;
            o.x = xv.x + (q.x - xv.x);
            o.y = xv.y + (q.y - xv.y);
            o.z = xv.z + (q.z - xv.z);
            o.w = xv.w + (q.w - xv.w);
            op[i] = o;
        }
    }
}

extern "C" void kernel_launch(void* const* d_in, const int* in_sizes, int n_in,
                              void* d_out, int out_size, void* d_ws, size_t ws_size,
                              hipStream_t stream) {
    const float* x_in = (const float*)d_in[0];   // [131072, 64]
    const float* emb  = (const float*)d_in[1];   // [64, 512]
    float* out = (float*)d_out;

    float* et   = (float*)d_ws;                  // [512, 64]
    float* bias = et + KC * DD;                  // [512]

    const int N = out_size / DD;                 // 131072 rows

    vq_prep<<<KC / 64, 256, 0, stream>>>(emb, et, bias);
    vq_main<<<N / RB, 256, 0, stream>>>(x_in, emb, et, bias, out);
}

// Round 6
// 135.686 us; speedup vs baseline: 14.1539x; 1.4025x over previous
//
#include <hip/hip_runtime.h>

// VectorQuantizer forward: out = codebook[argmin_k ||x - e_k||^2]
// inputs:  d_in[0] = inputs  [32,64,64,64] fp32  (N=131072 rows, D=64)
//          d_in[1] = embeddings [64,512] fp32    (D=64, K=512)
// out:     [32,64,64,64] fp32
//
// R6: split-bf16 MFMA. R5 was LDS-pipe-bound (3x ds_read_b128 per 32 fmac =
//     123 us floor on the per-CU LDS pipe). Scores now come from
//     mfma_f32_16x16x32_bf16 with x,e split hi+lo (3 terms, lo*lo dropped:
//     worst-case score error ~4e-5). Rows whose best1/best2 gap <= 5e-4 get
//     an exact fp32 wave-parallel recompute (numpy first-min tie-break), so
//     committed argmins are provably identical to fp32. Design is HBM-bound
//     (~96 MB moved).

#define KC 512
#define DD 64
#define TAU 5e-4f

typedef __attribute__((ext_vector_type(8))) short short8;
typedef __attribute__((ext_vector_type(4))) float float4v;

__device__ inline unsigned short f2bf(float f) {   // RNE bf16
    unsigned u = __float_as_uint(f);
    return (unsigned short)((u + 0x7FFF + ((u >> 16) & 1)) >> 16);
}
__device__ inline float bf2f(unsigned short b) {
    return __uint_as_float((unsigned)b << 16);
}

// Per code-tile ct (16 codes): bias (exact fp32, sequential d), et (fp32
// transposed codebook for gather/fallback), and Bh/Bl bf16 packs laid out in
// the exact 16x16x32 B-fragment order: element (lane l, j) = E[kc*32 +
// (l>>4)*8 + j][ct*16 + (l&15)].
__global__ __launch_bounds__(256) void vq_prep(const float* __restrict__ emb,
                                               float* __restrict__ et,
                                               float* __restrict__ bias,
                                               short* __restrict__ Bh,
                                               short* __restrict__ Bl) {
    __shared__ float tile[DD][17];
    const int ct = blockIdx.x;            // 0..31
    const int t  = threadIdx.x;

    {   // stage emb[d][ct*16..+16] -> tile[d][c]
        const int d = t >> 2, c0 = (t & 3) * 4;
        float4 v = *(const float4*)(emb + (size_t)d * KC + ct * 16 + c0);
        tile[d][c0 + 0] = v.x; tile[d][c0 + 1] = v.y;
        tile[d][c0 + 2] = v.z; tile[d][c0 + 3] = v.w;
    }
    __syncthreads();

    if (t < 16) {   // bias, exact sequential d-order
        float s = 0.f;
        #pragma unroll
        for (int d = 0; d < DD; ++d) { float v = tile[d][t]; s += v * v; }
        bias[ct * 16 + t] = s;
    }

    {   // et[(ct*16+c)][d0..d0+3]
        const int c = t >> 4, d0 = (t & 15) * 4;
        float4 v;
        v.x = tile[d0 + 0][c]; v.y = tile[d0 + 1][c];
        v.z = tile[d0 + 2][c]; v.w = tile[d0 + 3][c];
        *(float4*)(et + (size_t)(ct * 16 + c) * DD + d0) = v;
    }

    {   // B-fragment packs
        const int term = t >> 7;          // 0 = hi, 1 = lo
        const int kc   = (t >> 6) & 1;
        const int l    = t & 63;
        const int c    = l & 15, dq = l >> 4;
        short v8[8];
        #pragma unroll
        for (int j = 0; j < 8; ++j) {
            float f = tile[kc * 32 + dq * 8 + j][c];
            unsigned short h = f2bf(f);
            v8[j] = (short)(term == 0 ? h : f2bf(f - bf2f(h)));
        }
        short* dst = (term == 0 ? Bh : Bl) + ((size_t)(ct * 2 + kc) * 64 + l) * 8;
        *(short8*)dst = *(short8*)v8;
    }
}

__global__ __launch_bounds__(256) void vq_main(const float* __restrict__ x_in,
                                               const short* __restrict__ Bh,
                                               const short* __restrict__ Bl,
                                               const float* __restrict__ bias,
                                               const float* __restrict__ et,
                                               float* __restrict__ out) {
    __shared__ float bias_s[KC];
    __shared__ int   k1s[128];
    __shared__ float gaps[128];

    const int t = threadIdx.x, w = t >> 6, l = t & 63;
    const int col = l & 15, quad = l >> 4;
    const int R0 = blockIdx.x * 128;       // block covers 128 rows

    {   // stage bias into LDS
        float2 b2 = *(const float2*)(bias + 2 * t);
        bias_s[2 * t + 0] = b2.x; bias_s[2 * t + 1] = b2.y;
    }

    // A fragments (16x16x32 layout: m=lane&15, k=quad*8+j), rows split hi/lo.
    // Wave w owns rows [R0+w*32, R0+w*32+32) as two 16-row tiles.
    short8 ah[2][2], al[2][2];
    #pragma unroll
    for (int rt = 0; rt < 2; ++rt)
        #pragma unroll
        for (int kc = 0; kc < 2; ++kc) {
            const float* xp = x_in + (size_t)(R0 + w * 32 + rt * 16 + col) * DD
                            + kc * 32 + quad * 8;
            float4 xa = *(const float4*)xp;
            float4 xb = *(const float4*)(xp + 4);
            float f[8] = {xa.x, xa.y, xa.z, xa.w, xb.x, xb.y, xb.z, xb.w};
            #pragma unroll
            for (int j = 0; j < 8; ++j) {
                unsigned short h = f2bf(f[j]);
                ah[rt][kc][j] = (short)h;
                al[rt][kc][j] = (short)f2bf(f[j] - bf2f(h));
            }
        }
    __syncthreads();

    float v1[2][4], v2[2][4];
    int   k1[2][4];
    #pragma unroll
    for (int rt = 0; rt < 2; ++rt)
        #pragma unroll
        for (int r = 0; r < 4; ++r) {
            v1[rt][r] = 3.4e38f; v2[rt][r] = 3.4e38f; k1[rt][r] = 0;
        }

    #pragma unroll 2
    for (int ct = 0; ct < 32; ++ct) {
        short8 bh0 = *(const short8*)(Bh + ((size_t)(ct * 2 + 0) * 64 + l) * 8);
        short8 bh1 = *(const short8*)(Bh + ((size_t)(ct * 2 + 1) * 64 + l) * 8);
        short8 bl0 = *(const short8*)(Bl + ((size_t)(ct * 2 + 0) * 64 + l) * 8);
        short8 bl1 = *(const short8*)(Bl + ((size_t)(ct * 2 + 1) * 64 + l) * 8);
        float bs = bias_s[ct * 16 + col];
        const int kk = ct * 16 + col;
        #pragma unroll
        for (int rt = 0; rt < 2; ++rt) {
            float4v c = {0.f, 0.f, 0.f, 0.f};
            c = __builtin_amdgcn_mfma_f32_16x16x32_bf16(ah[rt][0], bh0, c, 0, 0, 0);
            c = __builtin_amdgcn_mfma_f32_16x16x32_bf16(ah[rt][1], bh1, c, 0, 0, 0);
            c = __builtin_amdgcn_mfma_f32_16x16x32_bf16(al[rt][0], bh0, c, 0, 0, 0);
            c = __builtin_amdgcn_mfma_f32_16x16x32_bf16(al[rt][1], bh1, c, 0, 0, 0);
            c = __builtin_amdgcn_mfma_f32_16x16x32_bf16(ah[rt][0], bl0, c, 0, 0, 0);
            c = __builtin_amdgcn_mfma_f32_16x16x32_bf16(ah[rt][1], bl1, c, 0, 0, 0);
            #pragma unroll
            for (int r = 0; r < 4; ++r) {
                float s = fmaf(c[r], -2.0f, bs);
                bool lt = s < v1[rt][r];                 // ascending ct: first-min
                v2[rt][r] = lt ? v1[rt][r] : fminf(v2[rt][r], s);
                k1[rt][r] = lt ? kk : k1[rt][r];
                v1[rt][r] = lt ? s : v1[rt][r];
            }
        }
    }

    // Reduce over the 16 col-lanes (C layout: row=(quad)*4+r, col=lane&15).
    #pragma unroll
    for (int rt = 0; rt < 2; ++rt)
        #pragma unroll
        for (int r = 0; r < 4; ++r) {
            float bv1 = v1[rt][r], bv2 = v2[rt][r];
            int   bk  = k1[rt][r];
            #pragma unroll
            for (int m = 1; m <= 8; m <<= 1) {
                float ov1 = __shfl_xor(bv1, m, 64);
                float ov2 = __shfl_xor(bv2, m, 64);
                int   ok  = __shfl_xor(bk,  m, 64);
                float nv2 = fminf(fminf(bv2, ov2), fmaxf(bv1, ov1));
                bool take = (ov1 < bv1) || (ov1 == bv1 && ok < bk);
                bv1 = take ? ov1 : bv1;
                bk  = take ? ok  : bk;
                bv2 = nv2;
            }
            if (col == 0) {
                int row_l = w * 32 + rt * 16 + quad * 4 + r;
                k1s[row_l]  = bk;
                gaps[row_l] = bv2 - bv1;
            }
        }

    // Exact fp32 fallback for near-tie rows (wave-uniform branch; rare).
    // Lane l scans codes [8l, 8l+8) ascending; cross-lane tie-break = lower k
    // => numpy first-min semantics, independent of the approx path.
    for (int rr = 0; rr < 32; ++rr) {
        const int row_l = w * 32 + rr;
        if (gaps[row_l] <= TAU) {
            const size_t grow = (size_t)(R0 + row_l) * DD;
            const int kbase = l * 8;
            float acc[8];
            #pragma unroll
            for (int j = 0; j < 8; ++j) acc[j] = 0.f;
            for (int d0 = 0; d0 < DD; d0 += 4) {
                float4 xv = *(const float4*)(x_in + grow + d0);
                #pragma unroll
                for (int j = 0; j < 8; ++j) {
                    float4 ev = *(const float4*)(et + (size_t)(kbase + j) * DD + d0);
                    acc[j] += xv.x * ev.x;
                    acc[j] += xv.y * ev.y;
                    acc[j] += xv.z * ev.z;
                    acc[j] += xv.w * ev.w;
                }
            }
            float4 b0 = *(const float4*)(bias + kbase);
            float4 b1 = *(const float4*)(bias + kbase + 4);
            float bb[8] = {b0.x, b0.y, b0.z, b0.w, b1.x, b1.y, b1.z, b1.w};
            float bv = 3.4e38f; int bk = 0;
            #pragma unroll
            for (int j = 0; j < 8; ++j) {
                float s = bb[j] - 2.f * acc[j];
                if (s < bv) { bv = s; bk = kbase + j; }
            }
            #pragma unroll
            for (int m = 1; m <= 32; m <<= 1) {
                float ov = __shfl_xor(bv, m, 64);
                int   ok = __shfl_xor(bk, m, 64);
                if (ov < bv || (ov == bv && ok < bk)) { bv = ov; bk = ok; }
            }
            if (l == 0) k1s[row_l] = bk;
        }
    }
    __syncthreads();

    // Gather epilogue: thread t writes half a row (32 floats). out = q
    // (x + (q-x) == q to ~5e-7 in fp32; threshold is 4.3e-3).
    {
        const int row_l = t >> 1, half = t & 1;
        const int bk = k1s[row_l];
        const float4* qp = (const float4*)(et + (size_t)bk * DD + half * 32);
        float4* op = (float4*)(out + (size_t)(R0 + row_l) * DD + half * 32);
        #pragma unroll
        for (int i = 0; i < 8; ++i) op[i] = qp[i];
    }
}

extern "C" void kernel_launch(void* const* d_in, const int* in_sizes, int n_in,
                              void* d_out, int out_size, void* d_ws, size_t ws_size,
                              hipStream_t stream) {
    const float* x_in = (const float*)d_in[0];   // [131072, 64]
    const float* emb  = (const float*)d_in[1];   // [64, 512]
    float* out = (float*)d_out;

    float* et   = (float*)d_ws;                       // 512*64 f32 = 131072 B
    float* bias = et + KC * DD;                       // 2048 B
    short* Bh   = (short*)(bias + KC);                // 32*2*64*8 shorts = 64 KB
    short* Bl   = Bh + 32 * 2 * 64 * 8;               // 64 KB

    const int N = out_size / DD;                      // 131072 rows

    vq_prep<<<32, 256, 0, stream>>>(emb, et, bias, Bh, Bl);
    vq_main<<<N / 128, 256, 0, stream>>>(x_in, Bh, Bl, bias, et, out);
}